// Round 1
// baseline (1076.135 us; speedup 1.0000x reference)
//
#include <hip/hip_runtime.h>

#define DIMC 256
#define HW 128
#define KTAPS 255

// One block per (n, c) channel image. 4 waves x 64 lanes.
// Stage 1 (vertical K=255 conv) -> Y in LDS (XOR-swizzled, 64KB)
// Stage 2 (horizontal K=255 conv) -> out.
// Each thread: 64 fp32 accumulators, 79-tap sliding weight window in regs.
__global__ __launch_bounds__(256, 2)
void sep_conv255_kernel(const float* __restrict__ x,
                        const float* __restrict__ wh,
                        const float* __restrict__ bh,
                        const float* __restrict__ ww,
                        const float* __restrict__ bw,
                        float* __restrict__ out) {
    __shared__ float ylds[HW * HW];  // exactly 64 KB

    const int blk  = blockIdx.x;        // n*DIMC + c
    const int c    = blk & (DIMC - 1);
    const int tid  = threadIdx.x;
    const int lane = tid & 63;
    const int wv   = tid >> 6;          // wave id 0..3

    const float* __restrict__ xc  = x   + (size_t)blk * (HW * HW);
    float*       __restrict__ zc  = out + (size_t)blk * (HW * HW);
    const float* __restrict__ whc = wh + c * KTAPS;
    const float* __restrict__ wwc = ww + c * KTAPS;

    // ---------------- Stage 1: vertical conv ----------------
    {
        const int w  = ((wv & 1) << 6) + lane;  // column owned by this thread
        const int h0 = (wv >> 1) << 6;          // output-row block base (wave-uniform)

        float acc[64];
        const float bias = bh[c];
#pragma unroll
        for (int i = 0; i < 64; ++i) acc[i] = bias;

        // win[t] = whc[64 + r - h0 + t] at r-block base r (t in [0,79))
        float win[79];
#pragma unroll
        for (int t = 0; t < 79; ++t) win[t] = whc[64 - h0 + t];

#pragma unroll 1
        for (int rb = 0; rb < 8; ++rb) {
            const int r = rb << 4;
            float xv[16];
#pragma unroll
            for (int j = 0; j < 16; ++j) xv[j] = xc[(r + j) * HW + w];
#pragma unroll
            for (int j = 0; j < 16; ++j) {
#pragma unroll
                for (int i = 0; i < 64; ++i)
                    acc[i] = fmaf(xv[j], win[63 + j - i], acc[i]);
            }
            if (rb < 7) {
#pragma unroll
                for (int t = 0; t < 63; ++t) win[t] = win[t + 16];
#pragma unroll
                for (int u = 0; u < 16; ++u)
                    win[63 + u] = whc[64 + (r + 16) - h0 + 63 + u];
            }
        }
        // Write Y to LDS, XOR bank swizzle; lanes differ in w -> conflict-free.
#pragma unroll
        for (int i = 0; i < 64; ++i) {
            const int h = h0 + i;
            ylds[h * HW + (w ^ (h & 31))] = acc[i];
        }
    }

    __syncthreads();

    // ---------------- Stage 2: horizontal conv ----------------
    {
        const int h  = ((wv & 1) << 6) + lane;  // row owned by this thread
        const int w0 = (wv >> 1) << 6;          // output-col block base (wave-uniform)

        float acc[64];
        const float bias = bw[c];
#pragma unroll
        for (int i = 0; i < 64; ++i) acc[i] = bias;

        float win[79];
#pragma unroll
        for (int t = 0; t < 79; ++t) win[t] = wwc[64 - w0 + t];

        const int hx = h & 31;
#pragma unroll 1
        for (int sb = 0; sb < 8; ++sb) {
            const int s = sb << 4;
            float yv[16];
#pragma unroll
            for (int j = 0; j < 16; ++j)
                yv[j] = ylds[h * HW + ((s + j) ^ hx)];
#pragma unroll
            for (int j = 0; j < 16; ++j) {
#pragma unroll
                for (int i = 0; i < 64; ++i)
                    acc[i] = fmaf(yv[j], win[63 + j - i], acc[i]);
            }
            if (sb < 7) {
#pragma unroll
                for (int t = 0; t < 63; ++t) win[t] = win[t + 16];
#pragma unroll
                for (int u = 0; u < 16; ++u)
                    win[63 + u] = wwc[64 + (s + 16) - w0 + 63 + u];
            }
        }
        // Store 64 consecutive outputs of row h as 16x float4.
#pragma unroll
        for (int k = 0; k < 16; ++k) {
            float4 v = make_float4(acc[4 * k], acc[4 * k + 1],
                                   acc[4 * k + 2], acc[4 * k + 3]);
            *reinterpret_cast<float4*>(&zc[h * HW + w0 + 4 * k]) = v;
        }
    }
}

extern "C" void kernel_launch(void* const* d_in, const int* in_sizes, int n_in,
                              void* d_out, int out_size, void* d_ws, size_t ws_size,
                              hipStream_t stream) {
    const float* x  = (const float*)d_in[0];
    const float* wh = (const float*)d_in[1];
    const float* bh = (const float*)d_in[2];
    const float* ww = (const float*)d_in[3];
    const float* bw = (const float*)d_in[4];
    float* outp = (float*)d_out;

    const int nbatch = in_sizes[0] / (DIMC * HW * HW);  // = 10
    dim3 grid(nbatch * DIMC);
    dim3 block(256);
    hipLaunchKernelGGL(sep_conv255_kernel, grid, block, 0, stream,
                       x, wh, bh, ww, bw, outp);
}

// Round 2
// 296.638 us; speedup vs baseline: 3.6278x; 3.6278x over previous
//
#include <hip/hip_runtime.h>

#define HW 128
#define KTAPS 255
#define DIMC 256

typedef short short8 __attribute__((ext_vector_type(8)));
typedef float f32x16 __attribute__((ext_vector_type(16)));

__device__ __forceinline__ short f2bf(float f) {
    return __builtin_bit_cast(short, (__bf16)f);
}
// Padded chunk addressing: 16B chunk index -> 16B slot (breaks 128B-stride bank collisions)
__device__ __forceinline__ int pad16(int c) { return c + (c >> 3); }

// Fragment layouts (v_mfma_f32_32x32x16_bf16):
//  A (MxK): elem(m,k): chunk=((m>>5)*8+(k>>4))*64 + (m&31)+32*((k>>3)&1), j=k&7
//  B (KxN): elem(k,n): chunk=((n>>5)*8+(k>>4))*64 + (n&31)+32*((k>>3)&1), j=k&7
//  C/D: col=lane&31, row=(reg&3)+8*(reg>>2)+4*(lane>>5)

__global__ __launch_bounds__(256, 2)
void sep_conv255_mfma(const float* __restrict__ x,
                      const float* __restrict__ wh,
                      const float* __restrict__ bh,
                      const float* __restrict__ ww,
                      const float* __restrict__ bw,
                      float* __restrict__ out) {
    __shared__ __align__(16) short P1[2304 * 8];  // X-frags, then Y-frags (36 KB)
    __shared__ __align__(16) short P2[2304 * 8];  // Ah-frags, then Bw-frags (36 KB)

    const int blk  = blockIdx.x;        // n*DIMC + c
    const int c    = blk & (DIMC - 1);
    const int tid  = threadIdx.x;
    const int lane = tid & 63;
    const int wv   = tid >> 6;          // wave id 0..3 -> tile-row m = 32*wv

    const float* __restrict__ xc  = x + (size_t)blk * (HW * HW);
    float* __restrict__ zc        = out + (size_t)blk * (HW * HW);
    const float* __restrict__ whc = wh + c * KTAPS;
    const float* __restrict__ wwc = ww + c * KTAPS;

    // ---------- Phase A: Ah frags -> P2, X bf16 frags -> P1 ----------
#pragma unroll
    for (int i = 0; i < 8; ++i) {
        const int ch = tid + (i << 8);          // chunk 0..2047
        const int lc = ch & 63;
        const int ks = (ch >> 6) & 7;
        const int tm = ch >> 9;
        const int m  = (tm << 5) + (lc & 31);
        const int kb = (ks << 4) + ((lc >> 5) << 3);
        const float* wp = whc + (127 + kb - m); // always in [0,247]
        short8 v;
#pragma unroll
        for (int j = 0; j < 8; ++j) v[j] = f2bf(wp[j]);
        *reinterpret_cast<short8*>(&P2[pad16(ch) * 8]) = v;
    }
    {
        // thread owns column n = tid&127; gathers 8 rows -> one packed b128 write
        const int n  = tid & 127;
        const int bc = (n >> 5) << 3;
#pragma unroll 2
        for (int i = 0; i < 8; ++i) {
            const int rg = (tid >> 7) + (i << 1);   // 0..15
            const int r0 = rg << 3;
            float xv[8];
#pragma unroll
            for (int j = 0; j < 8; ++j) xv[j] = xc[(r0 + j) * HW + n];
            short8 v;
#pragma unroll
            for (int j = 0; j < 8; ++j) v[j] = f2bf(xv[j]);
            const int ch = (bc + (r0 >> 4)) * 64 + (n & 31) + (((r0 >> 3) & 1) << 5);
            *reinterpret_cast<short8*>(&P1[pad16(ch) * 8]) = v;
        }
    }
    __syncthreads();

    // ---------- mm1: Y = Ah * X ----------
    f32x16 acc[4];
#pragma unroll
    for (int t = 0; t < 4; ++t)
#pragma unroll
        for (int j = 0; j < 16; ++j) acc[t][j] = 0.0f;

#pragma unroll
    for (int ks = 0; ks < 8; ++ks) {
        const short8 a = *reinterpret_cast<const short8*>(
            &P2[pad16(((wv << 3) + ks) * 64 + lane) * 8]);
#pragma unroll
        for (int t = 0; t < 4; ++t) {
            const short8 b = *reinterpret_cast<const short8*>(
                &P1[pad16(((t << 3) + ks) * 64 + lane) * 8]);
            acc[t] = __builtin_amdgcn_mfma_f32_32x32x16_bf16(a, b, acc[t], 0, 0, 0);
        }
    }
    __syncthreads();

    // ---------- Y(+bh) frags -> P1 ; Bw frags -> P2 ----------
    const float bhv = bh[c];
    {
        const int hbase = (wv << 5) + ((lane >> 5) << 2);
        const int s31   = lane & 31;
#pragma unroll
        for (int t = 0; t < 4; ++t) {
            const int s  = (t << 5) + s31;
            const int cb = ((wv << 3) + (s >> 4)) * 64 + (((s >> 3) & 1) << 5);
            const int jj = s & 7;
#pragma unroll
            for (int r = 0; r < 16; ++r) {
                const int h = hbase + (r & 3) + ((r >> 2) << 3);
                P1[pad16(cb + (h & 31)) * 8 + jj] = f2bf(acc[t][r] + bhv);
            }
        }
    }
#pragma unroll
    for (int i = 0; i < 8; ++i) {
        const int ch = tid + (i << 8);
        const int lc = ch & 63;
        const int ks = (ch >> 6) & 7;
        const int tn = ch >> 9;
        const int n  = (tn << 5) + (lc & 31);
        const int kb = (ks << 4) + ((lc >> 5) << 3);
        const float* wp = wwc + (127 + kb - n);
        short8 v;
#pragma unroll
        for (int j = 0; j < 8; ++j) v[j] = f2bf(wp[j]);
        *reinterpret_cast<short8*>(&P2[pad16(ch) * 8]) = v;
    }
    __syncthreads();

    // ---------- mm2: Z = Y * Bw ----------
#pragma unroll
    for (int t = 0; t < 4; ++t)
#pragma unroll
        for (int j = 0; j < 16; ++j) acc[t][j] = 0.0f;

#pragma unroll
    for (int ks = 0; ks < 8; ++ks) {
        const short8 a = *reinterpret_cast<const short8*>(
            &P1[pad16(((wv << 3) + ks) * 64 + lane) * 8]);
#pragma unroll
        for (int t = 0; t < 4; ++t) {
            const short8 b = *reinterpret_cast<const short8*>(
                &P2[pad16(((t << 3) + ks) * 64 + lane) * 8]);
            acc[t] = __builtin_amdgcn_mfma_f32_32x32x16_bf16(a, b, acc[t], 0, 0, 0);
        }
    }

    // ---------- epilogue: Z + bw -> global ----------
    const float bwv = bw[c];
    {
        const int hbase = (wv << 5) + ((lane >> 5) << 2);
        const int w31   = lane & 31;
#pragma unroll
        for (int t = 0; t < 4; ++t) {
            const int w2 = (t << 5) + w31;
#pragma unroll
            for (int r = 0; r < 16; ++r) {
                const int h = hbase + (r & 3) + ((r >> 2) << 3);
                zc[h * HW + w2] = acc[t][r] + bwv;
            }
        }
    }
}

extern "C" void kernel_launch(void* const* d_in, const int* in_sizes, int n_in,
                              void* d_out, int out_size, void* d_ws, size_t ws_size,
                              hipStream_t stream) {
    const float* x  = (const float*)d_in[0];
    const float* wh = (const float*)d_in[1];
    const float* bh = (const float*)d_in[2];
    const float* ww = (const float*)d_in[3];
    const float* bw = (const float*)d_in[4];
    float* outp = (float*)d_out;

    const int nbatch = in_sizes[0] / (DIMC * HW * HW);  // = 10
    dim3 grid(nbatch * DIMC);
    dim3 block(256);
    hipLaunchKernelGGL(sep_conv255_mfma, grid, block, 0, stream,
                       x, wh, bh, ww, bw, outp);
}